// Round 4
// baseline (507.844 us; speedup 1.0000x reference)
//
#include <hip/hip_runtime.h>
#include <stdint.h>

typedef unsigned short u16;
typedef __attribute__((ext_vector_type(8))) short short8;
typedef __attribute__((ext_vector_type(4))) float f32x4;

#define S_LEN 3072
#define D_DIM 2048
#define WIN 768
#define INV_SQRT_HD 0.08838834764831845f

__device__ __forceinline__ u16 f2bf(float x) {
  union { float f; uint32_t u; } v; v.f = x;
  uint32_t r = v.u + 0x7FFFu + ((v.u >> 16) & 1u);
  return (u16)(r >> 16);
}

__device__ __forceinline__ void load_lds16(const void* g, void* l) {
  __builtin_amdgcn_global_load_lds(
      (const __attribute__((address_space(1))) void*)g,
      (__attribute__((address_space(3))) void*)l, 16, 0, 0);
}

#define MFMA16(a, b, c) __builtin_amdgcn_mfma_f32_16x16x32_bf16((a), (b), (c), 0, 0, 0)

// ---------------- fp32 -> bf16 convert ----------------
__global__ __launch_bounds__(256) void k_cvt(const float* __restrict__ in,
                                             u16* __restrict__ out, int n4) {
  int i = blockIdx.x * 256 + threadIdx.x;
  if (i >= n4) return;
  float4 v = ((const float4*)in)[i];
  ushort4 o;
  o.x = f2bf(v.x); o.y = f2bf(v.y); o.z = f2bf(v.z); o.w = f2bf(v.w);
  ((ushort4*)out)[i] = o;
}

// ---------------- NT GEMM: C[i][j] = sum_k A[i][k]*B[j][k] + bias[j] ----------------
// A:[M][K] bf16, B:[N][K] bf16, 128x128 tile, BK=32, 4 waves, 16x16x32 MFMA. (m97 pattern)
template <bool BF16OUT>
__global__ __launch_bounds__(256) void k_gemm_nt(const u16* __restrict__ A,
                                                 const u16* __restrict__ B,
                                                 const float* __restrict__ bias,
                                                 void* __restrict__ Cv,
                                                 int M, int N, int K) {
  __shared__ u16 lA[128 * 32];
  __shared__ u16 lB[128 * 32];
  const int t = threadIdx.x;
  const int m0 = blockIdx.y * 128, n0 = blockIdx.x * 128;
  const int lane = t & 63, w = t >> 6, lo = lane & 15, g = lane >> 4;
  const int wr = w >> 1, wc = w & 1;
  const f32x4 zero4 = {0.f, 0.f, 0.f, 0.f};
  f32x4 acc[4][4];
#pragma unroll
  for (int m = 0; m < 4; ++m)
#pragma unroll
    for (int n = 0; n < 4; ++n) acc[m][n] = zero4;

  const u16* ga = A + (size_t)(m0 + (t >> 2)) * K + (t & 3) * 8;
  const u16* gb = B + (size_t)(n0 + (t >> 2)) * K + (t & 3) * 8;
  for (int k0 = 0; k0 < K; k0 += 32) {
    load_lds16(ga + k0, &lA[t * 8]);
    load_lds16(ga + (size_t)64 * K + k0, &lA[2048 + t * 8]);
    load_lds16(gb + k0, &lB[t * 8]);
    load_lds16(gb + (size_t)64 * K + k0, &lB[2048 + t * 8]);
    __syncthreads();
    short8 af[4], bfr[4];
#pragma unroll
    for (int m = 0; m < 4; ++m)
      af[m] = *(const short8*)&lA[(wr * 64 + m * 16 + lo) * 32 + g * 8];
#pragma unroll
    for (int n = 0; n < 4; ++n)
      bfr[n] = *(const short8*)&lB[(wc * 64 + n * 16 + lo) * 32 + g * 8];
#pragma unroll
    for (int m = 0; m < 4; ++m)
#pragma unroll
      for (int n = 0; n < 4; ++n) acc[m][n] = MFMA16(af[m], bfr[n], acc[m][n]);
    __syncthreads();
  }
#pragma unroll
  for (int m = 0; m < 4; ++m) {
    const int row = m0 + wr * 64 + m * 16 + 4 * g;
#pragma unroll
    for (int n = 0; n < 4; ++n) {
      const int col = n0 + wc * 64 + n * 16 + lo;
      const float bb = bias[col];
#pragma unroll
      for (int r = 0; r < 4; ++r) {
        const float val = acc[m][n][r] + bb;
        if (BF16OUT)
          ((u16*)Cv)[(size_t)(row + r) * N + col] = f2bf(val);
        else
          ((float*)Cv)[(size_t)(row + r) * N + col] = val;
      }
    }
  }
}

// ---------------- fused RMSNorm (bias pre-added) + RoPE -> bf16 ----------------
__global__ __launch_bounds__(256) void k_rms_rope(const float* __restrict__ H,
                                                  const float* __restrict__ gain,
                                                  const float* __restrict__ cosT,
                                                  const float* __restrict__ sinT,
                                                  u16* __restrict__ out) {
  const int s = blockIdx.x, t = threadIdx.x;
  const float* hp = H + (size_t)s * D_DIM + t * 8;
  float4 v0 = *(const float4*)hp;
  float4 v1 = *(const float4*)(hp + 4);
  float h[8] = {v0.x, v0.y, v0.z, v0.w, v1.x, v1.y, v1.z, v1.w};
  float ss = 0.f;
#pragma unroll
  for (int j = 0; j < 8; ++j) ss += h[j] * h[j];
#pragma unroll
  for (int off = 32; off > 0; off >>= 1) ss += __shfl_xor(ss, off);
  __shared__ float red[4];
  if ((t & 63) == 0) red[t >> 6] = ss;
  __syncthreads();
  ss = red[0] + red[1] + red[2] + red[3];
  const float rs = rsqrtf(ss * (1.f / D_DIM) + 1e-6f);
  const float4 g0 = *(const float4*)(gain + t * 8);
  const float4 g1 = *(const float4*)(gain + t * 8 + 4);
  float y[8];
  y[0] = h[0] * rs * g0.x; y[1] = h[1] * rs * g0.y;
  y[2] = h[2] * rs * g0.z; y[3] = h[3] * rs * g0.w;
  y[4] = h[4] * rs * g1.x; y[5] = h[5] * rs * g1.y;
  y[6] = h[6] * rs * g1.z; y[7] = h[7] * rs * g1.w;
  const int cbase = ((t * 8) & 127) >> 1;  // pair index within head
  short8 o8;
#pragma unroll
  for (int i = 0; i < 4; ++i) {
    const float cs = cosT[s * 64 + cbase + i];
    const float sn = sinT[s * 64 + cbase + i];
    const float yr = y[2 * i] * cs - y[2 * i + 1] * sn;
    const float yi = y[2 * i] * sn + y[2 * i + 1] * cs;
    o8[2 * i] = (short)f2bf(yr);
    o8[2 * i + 1] = (short)f2bf(yi);
  }
  *(short8*)(out + (size_t)s * D_DIM + t * 8) = o8;
}

// ---------------- bf16 transpose [S][D] -> [D][S] (64x64 tiles) ----------------
__global__ __launch_bounds__(256) void k_transpose(const u16* __restrict__ in,
                                                   u16* __restrict__ out) {
  __shared__ u16 tile[64][72];
  const int s0 = blockIdx.x * 64, d0 = blockIdx.y * 64;
  const int t = threadIdx.x;
  const int r = t >> 3, c8 = (t & 7) * 8;
#pragma unroll
  for (int p = 0; p < 2; ++p) {
    short8 v = *(const short8*)&in[(size_t)(s0 + r + p * 32) * D_DIM + d0 + c8];
#pragma unroll
    for (int j = 0; j < 8; ++j) tile[r + p * 32][c8 + j] = (u16)v[j];
  }
  __syncthreads();
#pragma unroll
  for (int p = 0; p < 2; ++p) {
    const int dr = r + p * 32;
    short8 o;
#pragma unroll
    for (int j = 0; j < 8; ++j) o[j] = (short)tile[c8 + j][dr];
    *(short8*)&out[(size_t)(d0 + dr) * S_LEN + s0 + c8] = o;
  }
}

// ---------------- banded flash attention ----------------
// grid (S/64, H); 4 waves, each wave owns 16 q-rows. KV-block = 32.
__global__ __launch_bounds__(256) void k_attn(const u16* __restrict__ Q,
                                              const u16* __restrict__ Kmat,
                                              const u16* __restrict__ Vt,
                                              u16* __restrict__ Om) {
  const int qt = blockIdx.x, h = blockIdx.y;
  const int t = threadIdx.x, w = t >> 6, lane = t & 63, lo = lane & 15, g = lane >> 4;
  const int qbase = qt * 64 + w * 16;
  const size_t hoff = (size_t)h * 128;
  __shared__ u16 ldsp[4][16][32];  // per-wave P tile (D-layout -> A-layout round trip)
  short8 qf[4];
  const u16* qp = Q + (size_t)(qbase + lo) * D_DIM + hoff + g * 8;
#pragma unroll
  for (int c = 0; c < 4; ++c) qf[c] = *(const short8*)(qp + c * 32);
  const f32x4 zero4 = {0.f, 0.f, 0.f, 0.f};
  f32x4 oacc[8];
#pragma unroll
  for (int ct = 0; ct < 8; ++ct) oacc[ct] = zero4;
  float mrun[4] = {-1e30f, -1e30f, -1e30f, -1e30f};
  float lrun[4] = {0.f, 0.f, 0.f, 0.f};
  int jlo = qt * 64 - WIN; if (jlo < 0) jlo = 0;
  int jhi = qt * 64 + 63 + WIN + 1; if (jhi > S_LEN) jhi = S_LEN;
  for (int j0 = jlo; j0 < jhi; j0 += 32) {
    f32x4 sc0 = zero4, sc1 = zero4;
    const u16* kp = Kmat + (size_t)(j0 + lo) * D_DIM + hoff + g * 8;
#pragma unroll
    for (int c = 0; c < 4; ++c) {
      short8 kf0 = *(const short8*)(kp + c * 32);
      short8 kf1 = *(const short8*)(kp + (size_t)16 * D_DIM + c * 32);
      sc0 = MFMA16(qf[c], kf0, sc0);
      sc1 = MFMA16(qf[c], kf1, sc1);
    }
    float alpha[4];
#pragma unroll
    for (int r = 0; r < 4; ++r) {
      const int qr = qbase + 4 * g + r;
      const int dk0 = (j0 + lo) - qr, dk1 = dk0 + 16;
      const bool ok0 = (dk0 <= WIN) && (dk0 >= -WIN);
      const bool ok1 = (dk1 <= WIN) && (dk1 >= -WIN);
      const float a0 = ok0 ? sc0[r] * INV_SQRT_HD : -1e30f;
      const float a1 = ok1 ? sc1[r] * INV_SQRT_HD : -1e30f;
      float mx = fmaxf(a0, a1);
#pragma unroll
      for (int off = 8; off > 0; off >>= 1) mx = fmaxf(mx, __shfl_xor(mx, off));
      const float mn = fmaxf(mrun[r], mx);
      const float al = __expf(mrun[r] - mn);
      const float p0 = ok0 ? __expf(a0 - mn) : 0.f;
      const float p1 = ok1 ? __expf(a1 - mn) : 0.f;
      float rsum = p0 + p1;
#pragma unroll
      for (int off = 8; off > 0; off >>= 1) rsum += __shfl_xor(rsum, off);
      mrun[r] = mn;
      lrun[r] = lrun[r] * al + rsum;
      alpha[r] = al;
      ldsp[w][4 * g + r][lo] = f2bf(p0);
      ldsp[w][4 * g + r][16 + lo] = f2bf(p1);
    }
#pragma unroll
    for (int ct = 0; ct < 8; ++ct) {
#pragma unroll
      for (int r = 0; r < 4; ++r) oacc[ct][r] *= alpha[r];
    }
    const short8 pf = *(const short8*)&ldsp[w][lo][g * 8];
    const u16* vp = Vt + (hoff + lo) * S_LEN + j0 + g * 8;
#pragma unroll
    for (int ct = 0; ct < 8; ++ct) {
      short8 vf = *(const short8*)(vp + (size_t)ct * 16 * S_LEN);
      oacc[ct] = MFMA16(pf, vf, oacc[ct]);
    }
  }
#pragma unroll
  for (int r = 0; r < 4; ++r) {
    const float inv = 1.f / lrun[r];
    const int row = qbase + 4 * g + r;
#pragma unroll
    for (int ct = 0; ct < 8; ++ct)
      Om[(size_t)row * D_DIM + hoff + ct * 16 + lo] = f2bf(oacc[ct][r] * inv);
  }
}

extern "C" void kernel_launch(void* const* d_in, const int* in_sizes, int n_in,
                              void* d_out, int out_size, void* d_ws, size_t ws_size,
                              hipStream_t stream) {
  // Inputs and output are fp32 (round-3 NaN proved inputs are not bf16;
  // rounds 1-2's identical 0.375 absmax was bf16-written-to-fp32-read d_out).
  const float* x    = (const float*)d_in[0];
  const float* wq   = (const float*)d_in[1];
  const float* bq   = (const float*)d_in[2];
  const float* wk   = (const float*)d_in[3];
  const float* bk   = (const float*)d_in[4];
  const float* wv   = (const float*)d_in[5];
  const float* bv   = (const float*)d_in[6];
  const float* wo   = (const float*)d_in[7];
  const float* bo   = (const float*)d_in[8];
  const float* gq   = (const float*)d_in[9];
  const float* gk   = (const float*)d_in[10];
  const float* cosT = (const float*)d_in[11];
  const float* sinT = (const float*)d_in[12];

  char* ws = (char*)d_ws;
  const size_t WB = (size_t)D_DIM * D_DIM * 2;  // bf16 weight: 8.4 MB
  const size_t XB = (size_t)S_LEN * D_DIM * 2;  // bf16 activation: 12.6 MB
  const size_t XF = (size_t)S_LEN * D_DIM * 4;  // fp32 activation: 25.2 MB
  u16*   wq_bf = (u16*)(ws);
  u16*   wk_bf = (u16*)(ws + WB);
  u16*   wv_bf = (u16*)(ws + 2 * WB);
  u16*   wo_bf = (u16*)(ws + 3 * WB);
  u16*   x_bf  = (u16*)(ws + 4 * WB);
  float* Q0    = (float*)(ws + 4 * WB + XB);
  float* K0    = (float*)(ws + 4 * WB + XB + XF);
  u16*   V0b   = (u16*)(ws + 4 * WB + XB + 2 * XF);
  // reuse (stream-ordered, producers strictly after last consumer of old contents):
  u16* q_bf = x_bf;        // x_bf dead after V GEMM
  u16* k_bf = wq_bf;       // wq_bf+wk_bf (16 MB) dead after Q,K GEMMs
  u16* vT   = (u16*)Q0;    // Q0 dead after rms_rope(Q)
  u16* attn = (u16*)K0;    // K0 dead after rms_rope(K)

  const int nw4 = (D_DIM * D_DIM) / 4;
  const int nx4 = (S_LEN * D_DIM) / 4;
  k_cvt<<<nx4 / 256, 256, 0, stream>>>(x, x_bf, nx4);
  k_cvt<<<nw4 / 256, 256, 0, stream>>>(wq, wq_bf, nw4);
  k_cvt<<<nw4 / 256, 256, 0, stream>>>(wk, wk_bf, nw4);
  k_cvt<<<nw4 / 256, 256, 0, stream>>>(wv, wv_bf, nw4);
  k_cvt<<<nw4 / 256, 256, 0, stream>>>(wo, wo_bf, nw4);

  dim3 ggrid(D_DIM / 128, S_LEN / 128);
  k_gemm_nt<false><<<ggrid, 256, 0, stream>>>(x_bf, wq_bf, bq, Q0, S_LEN, D_DIM, D_DIM);
  k_gemm_nt<false><<<ggrid, 256, 0, stream>>>(x_bf, wk_bf, bk, K0, S_LEN, D_DIM, D_DIM);
  k_gemm_nt<true ><<<ggrid, 256, 0, stream>>>(x_bf, wv_bf, bv, V0b, S_LEN, D_DIM, D_DIM);

  k_rms_rope<<<S_LEN, 256, 0, stream>>>(Q0, gq, cosT, sinT, q_bf);
  k_rms_rope<<<S_LEN, 256, 0, stream>>>(K0, gk, cosT, sinT, k_bf);
  k_transpose<<<dim3(S_LEN / 64, D_DIM / 64), 256, 0, stream>>>(V0b, vT);

  k_attn<<<dim3(S_LEN / 64, 16), 256, 0, stream>>>(q_bf, k_bf, vT, attn);

  // Final projection writes fp32 to d_out.
  k_gemm_nt<false><<<ggrid, 256, 0, stream>>>(attn, wo_bf, bo, (float*)d_out, S_LEN, D_DIM, D_DIM);
}